// Round 10
// baseline (690.439 us; speedup 1.0000x reference)
//
#include <hip/hip_runtime.h>
#include <hip/hip_cooperative_groups.h>
#include <stdint.h>

namespace cg = cooperative_groups;

typedef unsigned short u16;
typedef __bf16 bf16x8 __attribute__((ext_vector_type(8)));
typedef float f32x4 __attribute__((ext_vector_type(4)));

#define TTOK 2048
#define DIMSZ 1024
#define NROUT 16
#define INTERSZ 512
#define BK 128
#define CHK 16
#define SMEM_BYTES 49152   // 3 x 64 x 128 x 2B

__device__ __forceinline__ u16 f2bf(float f) {
    unsigned int u = __builtin_bit_cast(unsigned int, f);
    unsigned int r = u + 0x7FFFu + ((u >> 16) & 1u);
    return (u16)(r >> 16);
}

__device__ __forceinline__ ushort4 cvt4(float4 a) {
    ushort4 o;
    o.x = f2bf(a.x); o.y = f2bf(a.y); o.z = f2bf(a.z); o.w = f2bf(a.w);
    return o;
}

__device__ __forceinline__ void gl2lds16(const void* g, void* l) {
    __builtin_amdgcn_global_load_lds(
        (const __attribute__((address_space(1))) void*)(uintptr_t)g,
        (__attribute__((address_space(3))) void*)(uintptr_t)l,
        16, 0, 0);
}

// ================= phase bodies (verbatim from verified R5/R8/R9 kernels) ======

// ---- cast unit u in [0,2432): w1-group 1152, w3-group 1152, sw2 128 ----
__device__ __forceinline__ void cast_unit(
    int u, int tid,
    const float* __restrict__ w1, const float* __restrict__ sw1,
    const float* __restrict__ w3, const float* __restrict__ sw3,
    const float* __restrict__ sw2,
    u16* __restrict__ W1b, u16* __restrict__ W3b, u16* __restrict__ W2sb) {
    const float4* src; ushort4* dst; size_t gbase;
    if (u < 1152) {
        src = (u < 1024) ? (const float4*)w1
                         : (const float4*)sw1 - (size_t)1024 * 2048;
        dst = (ushort4*)W1b; gbase = (size_t)u * 2048;
    } else if (u < 2304) {
        int b = u - 1152;
        src = (b < 1024) ? (const float4*)w3
                         : (const float4*)sw3 - (size_t)1024 * 2048;
        dst = (ushort4*)W3b; gbase = (size_t)b * 2048;
    } else {
        int b = u - 2304;
        src = (const float4*)sw2; dst = (ushort4*)W2sb; gbase = (size_t)b * 2048;
    }
    float4 v[8];
    #pragma unroll
    for (int k = 0; k < 8; ++k) v[k] = src[gbase + k * 256 + tid];
    #pragma unroll
    for (int k = 0; k < 8; ++k) dst[gbase + k * 256 + tid] = cvt4(v[k]);
}

// ---- gate unit: one token; also zeroes the out row (atomic target) ----
__device__ __forceinline__ void gate_unit(
    int t, int tid, char* smem,
    const float* __restrict__ x, const float* __restrict__ gw,
    int* __restrict__ topi, float2* __restrict__ topw,
    u16* __restrict__ Xbf, float* __restrict__ out) {
    float* part = (float*)smem;           // 64 floats
    float* sfin = (float*)(smem + 256);   // 16 floats
    const int wave = tid >> 6, lane = tid & 63;
    const int d0 = tid * 4;
    *(float4*)(out + (size_t)t * DIMSZ + d0) = make_float4(0.f, 0.f, 0.f, 0.f);
    float4 xv = *(const float4*)(x + (size_t)t * DIMSZ + d0);
    *(ushort4*)&Xbf[(size_t)t * DIMSZ + d0] = cvt4(xv);

    float acc[16];
    #pragma unroll
    for (int e = 0; e < 16; ++e) {
        float4 g = *(const float4*)(gw + e * DIMSZ + d0);
        acc[e] = xv.x * g.x + xv.y * g.y + xv.z * g.z + xv.w * g.w;
    }
    #pragma unroll
    for (int off = 32; off > 0; off >>= 1) {
        #pragma unroll
        for (int e = 0; e < 16; ++e) acc[e] += __shfl_xor(acc[e], off);
    }
    if (lane < 16) part[wave * 16 + lane] = acc[lane];
    __syncthreads();
    if (wave == 0 && lane < 16) {
        float s = part[lane] + part[16 + lane] + part[32 + lane] + part[48 + lane];
        sfin[lane] = 1.f / (1.f + expf(-s));
    }
    __syncthreads();
    if (tid == 0) {
        int i0 = 0; float v0 = sfin[0];
        #pragma unroll
        for (int e = 1; e < 16; ++e) { float v = sfin[e]; if (v > v0) { v0 = v; i0 = e; } }
        int i1 = -1; float v1 = -1e30f;
        #pragma unroll
        for (int e = 0; e < 16; ++e) { float v = sfin[e]; if (e != i0 && v > v1) { v1 = v; i1 = e; } }
        float inv = 1.f / (v0 + v1);
        topi[t] = i0 | (i1 << 8);
        topw[t] = make_float2(v0 * inv, v1 * inv);
    }
    __syncthreads();
}

// ---- route body: expert e, block-wide prefix sum -> ordered compact lists ----
__device__ __forceinline__ void route_body(
    int e, int tid, char* smem,
    const int* __restrict__ topi, const float2* __restrict__ topw,
    int* __restrict__ counts, int* __restrict__ tokidx, float* __restrict__ tokw) {
    int* wsum = (int*)smem;
    int p[8]; int m[8]; int cnt = 0;
    #pragma unroll
    for (int j = 0; j < 8; ++j) {
        int t = tid * 8 + j;
        p[j] = topi[t];
        m[j] = ((p[j] & 255) == e) || ((p[j] >> 8) == e) ? 1 : 0;
        cnt += m[j];
    }
    const int lane = tid & 63, wave = tid >> 6;
    int v = cnt;
    #pragma unroll
    for (int off = 1; off < 64; off <<= 1) {
        int u = __shfl_up(v, off);
        if (lane >= off) v += u;
    }
    if (lane == 63) wsum[wave] = v;
    __syncthreads();
    int wbase = 0;
    #pragma unroll
    for (int w = 0; w < 4; ++w) wbase += (w < wave) ? wsum[w] : 0;
    int base = wbase + v - cnt;
    #pragma unroll
    for (int j = 0; j < 8; ++j) {
        if (m[j]) {
            int t = tid * 8 + j;
            float2 w2 = topw[t];
            tokidx[e * TTOK + base] = t;
            tokw[e * TTOK + base] = ((p[j] & 255) == e) ? w2.x : w2.y;
            ++base;
        }
    }
    if (tid == 0) counts[e] = wsum[0] + wsum[1] + wsum[2] + wsum[3];
}

// ---- gemm1 tile (R5 inner loop): BM=64 BN=64 BK=128, 4 waves ----
__device__ __forceinline__ void gemm1_tile(
    int id, int tid, char* smem,
    const u16* __restrict__ Xbf, const u16* __restrict__ W1b,
    const u16* __restrict__ W3b, const int* __restrict__ counts,
    const int* __restrict__ tokidx, const float* __restrict__ tokw,
    u16* __restrict__ Hc, u16* __restrict__ Hs) {
    int e, n0, m0;
    if (id < 4096) {
        e = id >> 8; int r2 = id & 255;
        n0 = (r2 >> 5) * 64; m0 = (r2 & 31) * 64;
    } else {
        int id2 = id - 4096;
        e = NROUT + (id2 >> 8); int r2 = id2 & 255;
        n0 = (r2 >> 5) * 64; m0 = (r2 & 31) * 64;
    }
    const int cnt = (e < NROUT) ? counts[e] : TTOK;
    if (m0 >= cnt) return;
    u16* As  = (u16*)smem;
    u16* B1s = (u16*)(smem + 16384);
    u16* B3s = (u16*)(smem + 32768);
    const u16* B1 = W1b + ((size_t)e * INTERSZ + n0) * DIMSZ;
    const u16* B3 = W3b + ((size_t)e * INTERSZ + n0) * DIMSZ;

    int row[4], cgs[4]; size_t arow[4];
    #pragma unroll
    for (int i = 0; i < 4; ++i) {
        int c = tid + i * 256;
        row[i] = c >> 4;
        cgs[i] = ((c & 15) ^ (row[i] & 7)) * 8;
        int slot = m0 + row[i];
        int g;
        if (e < NROUT) g = (slot < cnt) ? tokidx[e * TTOK + slot] : 0;
        else           g = slot;
        arow[i] = (size_t)g * DIMSZ;
    }
    f32x4 acc1[2][2] = {}; f32x4 acc3[2][2] = {};
    const int wave = tid >> 6, lane = tid & 63;
    const int wm = (wave >> 1) * 32, wn = (wave & 1) * 32;
    const int lr = lane & 15, lq = lane >> 4;

    for (int kt = 0; kt < DIMSZ / BK; ++kt) {
        const int k0 = kt * BK;
        #pragma unroll
        for (int i = 0; i < 4; ++i) {
            int c = tid + i * 256;
            gl2lds16(Xbf + arow[i] + k0 + cgs[i], &As[c * 8]);
            size_t boff = (size_t)row[i] * DIMSZ + k0 + cgs[i];
            gl2lds16(B1 + boff, &B1s[c * 8]);
            gl2lds16(B3 + boff, &B3s[c * 8]);
        }
        __syncthreads();
        #pragma unroll
        for (int ks = 0; ks < 4; ++ks) {
            bf16x8 af[2], b1f[2], b3f[2];
            const int g = ks * 4 + lq;
            #pragma unroll
            for (int mt = 0; mt < 2; ++mt) {
                int m = wm + mt * 16 + lr;
                af[mt] = *(const bf16x8*)&As[(m * CHK + (g ^ (m & 7))) * 8];
            }
            #pragma unroll
            for (int nt = 0; nt < 2; ++nt) {
                int n = wn + nt * 16 + lr;
                int ch = (n * CHK + (g ^ (n & 7))) * 8;
                b1f[nt] = *(const bf16x8*)&B1s[ch];
                b3f[nt] = *(const bf16x8*)&B3s[ch];
            }
            #pragma unroll
            for (int mt = 0; mt < 2; ++mt) {
                #pragma unroll
                for (int nt = 0; nt < 2; ++nt) {
                    acc1[mt][nt] = __builtin_amdgcn_mfma_f32_16x16x32_bf16(af[mt], b1f[nt], acc1[mt][nt], 0, 0, 0);
                    acc3[mt][nt] = __builtin_amdgcn_mfma_f32_16x16x32_bf16(af[mt], b3f[nt], acc3[mt][nt], 0, 0, 0);
                }
            }
        }
        __syncthreads();
    }
    #pragma unroll
    for (int mt = 0; mt < 2; ++mt) {
        #pragma unroll
        for (int nt = 0; nt < 2; ++nt) {
            #pragma unroll
            for (int r = 0; r < 4; ++r) {
                int m = wm + mt * 16 + lq * 4 + r;
                int n = wn + nt * 16 + lr;
                int slot = m0 + m;
                bool valid = slot < cnt;
                float h1 = acc1[mt][nt][r], h3 = acc3[mt][nt][r];
                float hv = 0.f;
                if (valid) {
                    float tw = (e < NROUT) ? tokw[e * TTOK + slot] : 1.0f;
                    hv = h1 / (1.f + __expf(-h1)) * h3 * tw;
                }
                if (e < NROUT)
                    Hc[((size_t)e * TTOK + slot) * INTERSZ + n0 + n] = f2bf(hv);
                else
                    Hs[(size_t)slot * DIMSZ + (e - NROUT) * INTERSZ + n0 + n] = f2bf(hv);
            }
        }
    }
}

// ---- gemm2 routed tile (R8 B-stationary, fp32 w2 direct), atomicAdd out ----
__device__ __forceinline__ void g2rt_tile(
    int u, int tid, char* smem,
    const u16* __restrict__ Hc, const float* __restrict__ w2f,
    const int* __restrict__ counts, const int* __restrict__ tokidx,
    float* __restrict__ out) {
    const int e = u >> 5;
    const int n0 = (u & 31) * 32;
    const int cnt = counts[e];
    u16* Bs = (u16*)smem;             // 32 KB: 32 rows x 64 chunks
    u16* As = (u16*)(smem + 32768);   // 16 KB

    const float4* B0 = (const float4*)(w2f + ((size_t)e * DIMSZ + n0) * INTERSZ);
    #pragma unroll
    for (int it2 = 0; it2 < 2; ++it2) {
        float4 v[8];
        #pragma unroll
        for (int k = 0; k < 8; ++k)
            v[k] = B0[(it2 * 8 + k) * 256 + tid];
        #pragma unroll
        for (int k = 0; k < 8; ++k) {
            int qq = (it2 * 8 + k) * 256 + tid;
            int brow = qq >> 7;
            int c = (qq & 127) >> 1;
            int h = qq & 1;
            *(ushort4*)&Bs[((brow << 6) + (c ^ (brow & 7))) * 8 + h * 4] = cvt4(v[k]);
        }
    }
    __syncthreads();

    const int wave = tid >> 6, lane = tid & 63;
    const int wm = (wave >> 1) * 32, wn = (wave & 1) * 16;
    const int lr = lane & 15, lq = lane >> 4;
    int row[4], cgs[4];
    #pragma unroll
    for (int i = 0; i < 4; ++i) {
        int c = tid + i * 256;
        row[i] = c >> 4;
        cgs[i] = ((c & 15) ^ (row[i] & 7)) * 8;
    }

    for (int m0 = 0; m0 < cnt; m0 += 64) {
        const u16* A0 = Hc + ((size_t)e * TTOK + m0) * INTERSZ;
        f32x4 acc[2] = {};
        for (int kt = 0; kt < INTERSZ / BK; ++kt) {
            const int k0 = kt * BK;
            #pragma unroll
            for (int i = 0; i < 4; ++i) {
                int c = tid + i * 256;
                gl2lds16(A0 + (size_t)row[i] * INTERSZ + k0 + cgs[i], &As[c * 8]);
            }
            __syncthreads();
            #pragma unroll
            for (int ks = 0; ks < 4; ++ks) {
                bf16x8 af[2], bfr;
                const int g = ks * 4 + lq;
                #pragma unroll
                for (int mt = 0; mt < 2; ++mt) {
                    int m = wm + mt * 16 + lr;
                    af[mt] = *(const bf16x8*)&As[(m * CHK + (g ^ (m & 7))) * 8];
                }
                {
                    int n = wn + lr;
                    bfr = *(const bf16x8*)&Bs[(n * 64 + kt * CHK + (g ^ (n & 7))) * 8];
                }
                #pragma unroll
                for (int mt = 0; mt < 2; ++mt) {
                    acc[mt] = __builtin_amdgcn_mfma_f32_16x16x32_bf16(af[mt], bfr, acc[mt], 0, 0, 0);
                }
            }
            __syncthreads();
        }
        #pragma unroll
        for (int mt = 0; mt < 2; ++mt) {
            #pragma unroll
            for (int r = 0; r < 4; ++r) {
                int m = wm + mt * 16 + lq * 4 + r;
                int slot = m0 + m;
                if (slot < cnt) {
                    int t = tokidx[e * TTOK + slot];
                    int n = wn + lr;
                    unsafeAtomicAdd(&out[(size_t)t * DIMSZ + n0 + n], acc[mt][r]);
                }
            }
        }
    }
}

// ---- gemm2 shared tile (R5 inner loop), atomicAdd out ----
__device__ __forceinline__ void g2sh_tile(
    int u, int tid, char* smem,
    const u16* __restrict__ Hs, const u16* __restrict__ W2sb,
    float* __restrict__ out) {
    const int m0 = (u >> 4) * 64;
    const int n0 = (u & 15) * 64;
    u16* As = (u16*)smem;
    u16* Bs = (u16*)(smem + 16384);
    const u16* A0 = Hs + (size_t)m0 * DIMSZ;
    const u16* B0 = W2sb + (size_t)n0 * DIMSZ;
    const int wave = tid >> 6, lane = tid & 63;
    const int wm = (wave >> 1) * 32, wn = (wave & 1) * 32;
    const int lr = lane & 15, lq = lane >> 4;

    int row[4], cgs[4];
    #pragma unroll
    for (int i = 0; i < 4; ++i) {
        int c = tid + i * 256;
        row[i] = c >> 4;
        cgs[i] = ((c & 15) ^ (row[i] & 7)) * 8;
    }

    f32x4 acc[2][2] = {};
    for (int kt = 0; kt < DIMSZ / BK; ++kt) {
        const int k0 = kt * BK;
        #pragma unroll
        for (int i = 0; i < 4; ++i) {
            int c = tid + i * 256;
            gl2lds16(A0 + (size_t)row[i] * DIMSZ + k0 + cgs[i], &As[c * 8]);
            gl2lds16(B0 + (size_t)row[i] * DIMSZ + k0 + cgs[i], &Bs[c * 8]);
        }
        __syncthreads();
        #pragma unroll
        for (int ks = 0; ks < 4; ++ks) {
            bf16x8 af[2], bfr[2];
            const int g = ks * 4 + lq;
            #pragma unroll
            for (int mt = 0; mt < 2; ++mt) {
                int m = wm + mt * 16 + lr;
                af[mt] = *(const bf16x8*)&As[(m * CHK + (g ^ (m & 7))) * 8];
            }
            #pragma unroll
            for (int nt = 0; nt < 2; ++nt) {
                int n = wn + nt * 16 + lr;
                bfr[nt] = *(const bf16x8*)&Bs[(n * CHK + (g ^ (n & 7))) * 8];
            }
            #pragma unroll
            for (int mt = 0; mt < 2; ++mt) {
                #pragma unroll
                for (int nt = 0; nt < 2; ++nt) {
                    acc[mt][nt] = __builtin_amdgcn_mfma_f32_16x16x32_bf16(af[mt], bfr[nt], acc[mt][nt], 0, 0, 0);
                }
            }
        }
        __syncthreads();
    }
    #pragma unroll
    for (int mt = 0; mt < 2; ++mt) {
        #pragma unroll
        for (int r = 0; r < 4; ++r) {
            int t = m0 + wm + mt * 16 + lq * 4 + r;
            #pragma unroll
            for (int nt = 0; nt < 2; ++nt) {
                int n = wn + nt * 16 + lr;
                unsafeAtomicAdd(&out[(size_t)t * DIMSZ + n0 + n], acc[mt][nt][r]);
            }
        }
    }
}

// ================= cooperative mega-kernel =================
__global__ __launch_bounds__(256, 3) void mega(
    const float* __restrict__ x, const float* __restrict__ gw,
    const float* __restrict__ w1, const float* __restrict__ w3,
    const float* __restrict__ sw1, const float* __restrict__ sw3,
    const float* __restrict__ sw2, const float* __restrict__ w2f,
    u16* __restrict__ W1b, u16* __restrict__ W3b, u16* __restrict__ W2sb,
    u16* __restrict__ Xbf, int* __restrict__ topi, float2* __restrict__ topw,
    int* __restrict__ counts, int* __restrict__ tokidx, float* __restrict__ tokw,
    u16* __restrict__ Hc, u16* __restrict__ Hs, float* __restrict__ out) {
    cg::grid_group grid = cg::this_grid();
    const int tid = threadIdx.x;
    const int nb = gridDim.x;
    __shared__ char smem[SMEM_BYTES];

    // phase 1: weight casts + gate/Xbf/out-zero
    for (int u = blockIdx.x; u < 2432 + TTOK; u += nb) {
        if (u < 2432) cast_unit(u, tid, w1, sw1, w3, sw3, sw2, W1b, W3b, W2sb);
        else          gate_unit(u - 2432, tid, smem, x, gw, topi, topw, Xbf, out);
    }
    __threadfence(); grid.sync(); __threadfence();

    // phase 2: route
    if (blockIdx.x < NROUT)
        route_body(blockIdx.x, tid, smem, topi, topw, counts, tokidx, tokw);
    __threadfence(); grid.sync(); __threadfence();

    // phase 3: gemm1 (routed + shared halves), 4608 tiles
    for (int u = blockIdx.x; u < 4608; u += nb)
        gemm1_tile(u, tid, smem, Xbf, W1b, W3b, counts, tokidx, tokw, Hc, Hs);
    __threadfence(); grid.sync(); __threadfence();

    // phase 4: gemm2 routed (512 B-stationary tiles) + shared (512 tiles)
    for (int u = blockIdx.x; u < 1024; u += nb) {
        if (u < 512) g2rt_tile(u, tid, smem, Hc, w2f, counts, tokidx, out);
        else         g2sh_tile(u - 512, tid, smem, Hs, W2sb, out);
    }
}

// ================= fallback phase kernels (non-cooperative) =================
__global__ __launch_bounds__(256, 3) void p1k(
    const float* __restrict__ x, const float* __restrict__ gw,
    const float* __restrict__ w1, const float* __restrict__ w3,
    const float* __restrict__ sw1, const float* __restrict__ sw3,
    const float* __restrict__ sw2,
    u16* __restrict__ W1b, u16* __restrict__ W3b, u16* __restrict__ W2sb,
    u16* __restrict__ Xbf, int* __restrict__ topi, float2* __restrict__ topw,
    float* __restrict__ out) {
    __shared__ char smem[512];
    const int tid = threadIdx.x;
    for (int u = blockIdx.x; u < 2432 + TTOK; u += gridDim.x) {
        if (u < 2432) cast_unit(u, tid, w1, sw1, w3, sw3, sw2, W1b, W3b, W2sb);
        else          gate_unit(u - 2432, tid, smem, x, gw, topi, topw, Xbf, out);
    }
}
__global__ __launch_bounds__(256) void p2k(
    const int* __restrict__ topi, const float2* __restrict__ topw,
    int* __restrict__ counts, int* __restrict__ tokidx, float* __restrict__ tokw) {
    __shared__ char smem[64];
    route_body(blockIdx.x, threadIdx.x, smem, topi, topw, counts, tokidx, tokw);
}
__global__ __launch_bounds__(256, 3) void p3k(
    const u16* __restrict__ Xbf, const u16* __restrict__ W1b,
    const u16* __restrict__ W3b, const int* __restrict__ counts,
    const int* __restrict__ tokidx, const float* __restrict__ tokw,
    u16* __restrict__ Hc, u16* __restrict__ Hs) {
    __shared__ char smem[SMEM_BYTES];
    for (int u = blockIdx.x; u < 4608; u += gridDim.x)
        gemm1_tile(u, threadIdx.x, smem, Xbf, W1b, W3b, counts, tokidx, tokw, Hc, Hs);
}
__global__ __launch_bounds__(256, 3) void p4k(
    const u16* __restrict__ Hc, const float* __restrict__ w2f,
    const u16* __restrict__ Hs, const u16* __restrict__ W2sb,
    const int* __restrict__ counts, const int* __restrict__ tokidx,
    float* __restrict__ out) {
    __shared__ char smem[SMEM_BYTES];
    for (int u = blockIdx.x; u < 1024; u += gridDim.x) {
        if (u < 512) g2rt_tile(u, threadIdx.x, smem, Hc, w2f, counts, tokidx, out);
        else         g2sh_tile(u - 512, threadIdx.x, smem, Hs, W2sb, out);
    }
}

extern "C" void kernel_launch(void* const* d_in, const int* in_sizes, int n_in,
                              void* d_out, int out_size, void* d_ws, size_t ws_size,
                              hipStream_t stream) {
    const float* x      = (const float*)d_in[0];
    const float* gate_w = (const float*)d_in[1];
    const float* w1     = (const float*)d_in[2];
    const float* w2     = (const float*)d_in[3];
    const float* w3     = (const float*)d_in[4];
    const float* sw1    = (const float*)d_in[5];
    const float* sw2    = (const float*)d_in[6];
    const float* sw3    = (const float*)d_in[7];
    float* out = (float*)d_out;

    char* ws = (char*)d_ws;
    const size_t SZ_W   = (size_t)(NROUT + 2) * INTERSZ * DIMSZ * 2;
    const size_t SZ_XBF = (size_t)TTOK * DIMSZ * 2;
    u16*   W1b    = (u16*)(ws);
    u16*   W3b    = (u16*)(ws + SZ_W);
    u16*   W2all  = (u16*)(ws + 2 * SZ_W);   // only the W2sb (sw2) region used
    u16*   Xbf    = (u16*)(ws + 3 * SZ_W);
    char*  route  = ws + 3 * SZ_W + SZ_XBF;
    int*   counts = (int*)route;
    int*   topi   = (int*)(route + 256);
    float2* topw  = (float2*)(route + 256 + TTOK * 4);
    int*   tokidx = (int*)(route + 256 + TTOK * 12);
    float* tokw   = (float*)(route + 256 + TTOK * 12 + 16 * TTOK * 4);
    char*  hbuf   = route + 256 + TTOK * 12 + 2 * (size_t)16 * TTOK * 4;
    u16*   Hc     = (u16*)hbuf;                                        // [16][2048][512]
    u16*   Hs     = (u16*)(hbuf + (size_t)NROUT * TTOK * INTERSZ * 2); // [2048][1024]
    u16*   W2sb   = W2all + (size_t)NROUT * DIMSZ * INTERSZ;

    // try cooperative mega-kernel first
    int maxb = 0;
    hipError_t qe = hipOccupancyMaxActiveBlocksPerMultiprocessor(
        &maxb, reinterpret_cast<const void*>(mega), 256, 0);
    bool done = false;
    if (qe == hipSuccess && maxb >= 1) {
        int nblk = maxb * 256;          // 256 CUs on MI355X
        if (nblk > 4480) nblk = 4480;
        void* args[] = {
            (void*)&x, (void*)&gate_w, (void*)&w1, (void*)&w3,
            (void*)&sw1, (void*)&sw3, (void*)&sw2, (void*)&w2,
            (void*)&W1b, (void*)&W3b, (void*)&W2sb,
            (void*)&Xbf, (void*)&topi, (void*)&topw,
            (void*)&counts, (void*)&tokidx, (void*)&tokw,
            (void*)&Hc, (void*)&Hs, (void*)&out };
        hipError_t le = hipLaunchCooperativeKernel(
            reinterpret_cast<const void*>(mega), dim3(nblk), dim3(256),
            args, 0, stream);
        done = (le == hipSuccess);
    }
    if (!done) {
        // fallback: same bodies, 4 sequential launches
        p1k<<<dim3(768), 256, 0, stream>>>(
            x, gate_w, w1, w3, sw1, sw3, sw2, W1b, W3b, W2sb,
            Xbf, topi, topw, out);
        p2k<<<dim3(NROUT), 256, 0, stream>>>(topi, topw, counts, tokidx, tokw);
        p3k<<<dim3(4608), 256, 0, stream>>>(
            Xbf, W1b, W3b, counts, tokidx, tokw, Hc, Hs);
        p4k<<<dim3(1024), 256, 0, stream>>>(
            Hc, w2, Hs, W2sb, counts, tokidx, out);
    }
}

// Round 11
// 241.700 us; speedup vs baseline: 2.8566x; 2.8566x over previous
//
#include <hip/hip_runtime.h>
#include <stdint.h>

typedef unsigned short u16;
typedef __bf16 bf16x8 __attribute__((ext_vector_type(8)));
typedef float f32x4 __attribute__((ext_vector_type(4)));
typedef unsigned short u16x8 __attribute__((ext_vector_type(8)));

#define TTOK 2048
#define DIMSZ 1024
#define NROUT 16
#define INTERSZ 512
#define BK 128
#define CHK 16   // BK/8 chunks of 8 u16 per row

__device__ __forceinline__ u16 f2bf(float f) {
    unsigned int u = __builtin_bit_cast(unsigned int, f);
    unsigned int r = u + 0x7FFFu + ((u >> 16) & 1u);
    return (u16)(r >> 16);
}

__device__ __forceinline__ void gl2lds16(const void* g, void* l) {
    __builtin_amdgcn_global_load_lds(
        (const __attribute__((address_space(1))) void*)(uintptr_t)g,
        (__attribute__((address_space(3))) void*)(uintptr_t)l,
        16, 0, 0);
}

// ---- prep: grid.y<3 = weight cast groups; grid.y==3 = gate + Xbf ----
#define NF4A (NROUT * INTERSZ * DIMSZ / 4)   // 2,097,152 float4s (routed group)
#define NF4B (DIMSZ * DIMSZ / 4)             // 262,144 float4s (shared group)
#define CASTA_BLKS 1024                      // NF4A / 2048
#define CAST_BLKS 1152                       // + NF4B / 2048
__global__ __launch_bounds__(256) void prep(
    const float* __restrict__ w1, const float* __restrict__ sw1,
    const float* __restrict__ w3, const float* __restrict__ sw3,
    const float* __restrict__ w2, const float* __restrict__ sw2,
    u16* __restrict__ W1b, u16* __restrict__ W3b, u16* __restrict__ W2b,
    const float* __restrict__ x, const float* __restrict__ gw,
    int* __restrict__ topi, float2* __restrict__ topw,
    u16* __restrict__ Xbf) {
    const int r = blockIdx.y;
    const int tid = threadIdx.x;
    if (r < 3) {
        if (blockIdx.x >= CAST_BLKS) return;
        const float* a; const float* b; u16* d;
        if (r == 0)      { a = w1; b = sw1; d = W1b; }
        else if (r == 1) { a = w3; b = sw3; d = W3b; }
        else             { a = w2; b = sw2; d = W2b; }
        const float4* src = (blockIdx.x < CASTA_BLKS)
                            ? (const float4*)a
                            : (const float4*)b - (size_t)CASTA_BLKS * 2048;
        ushort4* dst = (ushort4*)d;
        const size_t gbase = (size_t)blockIdx.x * 2048;
        float4 v[8];
        #pragma unroll
        for (int k = 0; k < 8; ++k)
            v[k] = src[gbase + k * 256 + tid];
        #pragma unroll
        for (int k = 0; k < 8; ++k) {
            ushort4 o;
            o.x = f2bf(v[k].x); o.y = f2bf(v[k].y);
            o.z = f2bf(v[k].z); o.w = f2bf(v[k].w);
            dst[gbase + k * 256 + tid] = o;
        }
        return;
    }
    // gate branch: one block per token
    const int t = blockIdx.x;
    const int wave = tid >> 6, lane = tid & 63;
    const int d0 = tid * 4;
    float4 xv = *(const float4*)(x + (size_t)t * DIMSZ + d0);
    ushort4 o;
    o.x = f2bf(xv.x); o.y = f2bf(xv.y); o.z = f2bf(xv.z); o.w = f2bf(xv.w);
    *(ushort4*)&Xbf[(size_t)t * DIMSZ + d0] = o;

    float acc[16];
    #pragma unroll
    for (int e = 0; e < 16; ++e) {
        float4 g = *(const float4*)(gw + e * DIMSZ + d0);
        acc[e] = xv.x * g.x + xv.y * g.y + xv.z * g.z + xv.w * g.w;
    }
    #pragma unroll
    for (int off = 32; off > 0; off >>= 1) {
        #pragma unroll
        for (int e = 0; e < 16; ++e) acc[e] += __shfl_xor(acc[e], off);
    }
    __shared__ float part[4][16];
    __shared__ float sfin[16];
    if (lane < 16) part[wave][lane] = acc[lane];
    __syncthreads();
    if (wave == 0 && lane < 16) {
        float s = part[0][lane] + part[1][lane] + part[2][lane] + part[3][lane];
        sfin[lane] = 1.f / (1.f + expf(-s));
    }
    __syncthreads();
    if (tid == 0) {
        int i0 = 0; float v0 = sfin[0];
        #pragma unroll
        for (int e = 1; e < 16; ++e) { float v = sfin[e]; if (v > v0) { v0 = v; i0 = e; } }
        int i1 = -1; float v1 = -1e30f;
        #pragma unroll
        for (int e = 0; e < 16; ++e) { float v = sfin[e]; if (e != i0 && v > v1) { v1 = v; i1 = e; } }
        float inv = 1.f / (v0 + v1);
        topi[t] = i0 | (i1 << 8);
        topw[t] = make_float2(v0 * inv, v1 * inv);
    }
}

// ---- route: one block per expert; block-wide prefix sum -> ordered compact lists ----
__global__ __launch_bounds__(256) void route_kernel(
    const int* __restrict__ topi, const float2* __restrict__ topw,
    int* __restrict__ counts, int* __restrict__ tokidx, float* __restrict__ tokw) {
    const int e = blockIdx.x;
    const int tid = threadIdx.x;
    int p[8]; int m[8]; int cnt = 0;
    #pragma unroll
    for (int j = 0; j < 8; ++j) {
        int t = tid * 8 + j;
        p[j] = topi[t];
        m[j] = ((p[j] & 255) == e) || ((p[j] >> 8) == e) ? 1 : 0;
        cnt += m[j];
    }
    const int lane = tid & 63, wave = tid >> 6;
    int v = cnt;
    #pragma unroll
    for (int off = 1; off < 64; off <<= 1) {
        int u = __shfl_up(v, off);
        if (lane >= off) v += u;
    }
    __shared__ int wsum[4];
    if (lane == 63) wsum[wave] = v;
    __syncthreads();
    int wbase = 0;
    #pragma unroll
    for (int w = 0; w < 4; ++w) wbase += (w < wave) ? wsum[w] : 0;
    int base = wbase + v - cnt;
    #pragma unroll
    for (int j = 0; j < 8; ++j) {
        if (m[j]) {
            int t = tid * 8 + j;
            float2 w2 = topw[t];
            tokidx[e * TTOK + base] = t;
            tokw[e * TTOK + base] = ((p[j] & 255) == e) ? w2.x : w2.y;
            ++base;
        }
    }
    if (tid == 0) counts[e] = wsum[0] + wsum[1] + wsum[2] + wsum[3];
}

// ---- GEMM1 sparse: BM=128 BN=64 BK=128, 4 waves (2x2), wave tile 64x32 ----
// 64 MFMA per barrier-pair (4x the old 64x64 tile) at 64 KB LDS, 2 blocks/CU.
// K-accumulation order identical to the 64x64 version (kt asc, ks asc).
__global__ __launch_bounds__(256) void gemm1s(
    const u16* __restrict__ Xbf, const u16* __restrict__ W1b,
    const u16* __restrict__ W3b, const int* __restrict__ counts,
    const int* __restrict__ tokidx, const float* __restrict__ tokw,
    u16* __restrict__ Hc, u16* __restrict__ Hs) {
    const int e = blockIdx.z;
    const int cnt = (e < NROUT) ? counts[e] : TTOK;
    const int m0 = blockIdx.y * 128;
    if (m0 >= cnt) return;
    const int n0 = blockIdx.x * 64;
    __shared__ u16 As[128 * BK], B1s[64 * BK], B3s[64 * BK];  // 32+16+16 KB
    const u16* B1 = W1b + ((size_t)e * INTERSZ + n0) * DIMSZ;
    const u16* B3 = W3b + ((size_t)e * INTERSZ + n0) * DIMSZ;
    const int tid = threadIdx.x;

    // A staging: 8 chunks/thread over 128 rows x 16 chunks
    int cgsa[8]; size_t arow[8];
    #pragma unroll
    for (int i = 0; i < 8; ++i) {
        int c = tid + i * 256;
        int rowa = c >> 4;
        cgsa[i] = ((c & 15) ^ (rowa & 7)) * 8;
        int slot = m0 + rowa;
        int g;
        if (e < NROUT) g = (slot < cnt) ? tokidx[e * TTOK + slot] : 0;
        else           g = slot;
        arow[i] = (size_t)g * DIMSZ;
    }
    // B staging: 4 chunks/thread over 64 rows x 16 chunks
    int rowb[4], cgsb[4];
    #pragma unroll
    for (int i = 0; i < 4; ++i) {
        int c = tid + i * 256;
        rowb[i] = c >> 4;
        cgsb[i] = ((c & 15) ^ (rowb[i] & 7)) * 8;
    }
    f32x4 acc1[4][2] = {}; f32x4 acc3[4][2] = {};
    const int wave = tid >> 6, lane = tid & 63;
    const int wm = (wave >> 1) * 64, wn = (wave & 1) * 32;
    const int lr = lane & 15, lq = lane >> 4;

    for (int kt = 0; kt < DIMSZ / BK; ++kt) {
        const int k0 = kt * BK;
        #pragma unroll
        for (int i = 0; i < 8; ++i) {
            int c = tid + i * 256;
            gl2lds16(Xbf + arow[i] + k0 + cgsa[i], &As[c * 8]);
        }
        #pragma unroll
        for (int i = 0; i < 4; ++i) {
            int c = tid + i * 256;
            size_t boff = (size_t)rowb[i] * DIMSZ + k0 + cgsb[i];
            gl2lds16(B1 + boff, &B1s[c * 8]);
            gl2lds16(B3 + boff, &B3s[c * 8]);
        }
        __syncthreads();
        #pragma unroll
        for (int ks = 0; ks < 4; ++ks) {
            bf16x8 af[4], b1f[2], b3f[2];
            const int g = ks * 4 + lq;
            #pragma unroll
            for (int mt = 0; mt < 4; ++mt) {
                int m = wm + mt * 16 + lr;
                af[mt] = *(const bf16x8*)&As[(m * CHK + (g ^ (m & 7))) * 8];
            }
            #pragma unroll
            for (int nt = 0; nt < 2; ++nt) {
                int n = wn + nt * 16 + lr;
                int ch = (n * CHK + (g ^ (n & 7))) * 8;
                b1f[nt] = *(const bf16x8*)&B1s[ch];
                b3f[nt] = *(const bf16x8*)&B3s[ch];
            }
            #pragma unroll
            for (int mt = 0; mt < 4; ++mt) {
                #pragma unroll
                for (int nt = 0; nt < 2; ++nt) {
                    acc1[mt][nt] = __builtin_amdgcn_mfma_f32_16x16x32_bf16(af[mt], b1f[nt], acc1[mt][nt], 0, 0, 0);
                    acc3[mt][nt] = __builtin_amdgcn_mfma_f32_16x16x32_bf16(af[mt], b3f[nt], acc3[mt][nt], 0, 0, 0);
                }
            }
        }
        __syncthreads();
    }
    #pragma unroll
    for (int mt = 0; mt < 4; ++mt) {
        #pragma unroll
        for (int nt = 0; nt < 2; ++nt) {
            #pragma unroll
            for (int r = 0; r < 4; ++r) {
                int m = wm + mt * 16 + lq * 4 + r;
                int n = wn + nt * 16 + lr;
                int slot = m0 + m;
                bool valid = slot < cnt;
                float h1 = acc1[mt][nt][r], h3 = acc3[mt][nt][r];
                float hv = 0.f;
                if (valid) {
                    float tw = (e < NROUT) ? tokw[e * TTOK + slot] : 1.0f;
                    hv = h1 / (1.f + __expf(-h1)) * h3 * tw;
                }
                if (e < NROUT) {
                    if (valid)
                        Hc[((size_t)e * TTOK + slot) * INTERSZ + n0 + n] = f2bf(hv);
                } else {
                    Hs[(size_t)slot * DIMSZ + (e - NROUT) * INTERSZ + n0 + n] = f2bf(hv);
                }
            }
        }
    }
}

// ---- GEMM2 routed: BM=64 BN=64 BK=128, K=512 (R5-proven). NO atomics: each
// token's top-1 expert block plain-stores its row into bufA, top-2 into bufB.
__global__ __launch_bounds__(256) void gemm2rt(
    const u16* __restrict__ Hc, const u16* __restrict__ W2b,
    const int* __restrict__ counts, const int* __restrict__ tokidx,
    const int* __restrict__ topi,
    float* __restrict__ bufA, float* __restrict__ bufB) {
    const int e = blockIdx.z;
    const int cnt = counts[e];
    const int m0 = blockIdx.y * 64;
    if (m0 >= cnt) return;
    const int n0 = blockIdx.x * 64;
    __shared__ u16 As[64 * BK], Bs[64 * BK];
    const u16* A0 = Hc + ((size_t)e * TTOK + m0) * INTERSZ;
    const u16* B0 = W2b + ((size_t)e * DIMSZ + n0) * INTERSZ;
    const int tid = threadIdx.x;
    const int wave = tid >> 6, lane = tid & 63;
    const int wm = (wave >> 1) * 32, wn = (wave & 1) * 32;
    const int lr = lane & 15, lq = lane >> 4;

    int row[4], cgs[4];
    #pragma unroll
    for (int i = 0; i < 4; ++i) {
        int c = tid + i * 256;
        row[i] = c >> 4;
        cgs[i] = ((c & 15) ^ (row[i] & 7)) * 8;
    }

    f32x4 acc[2][2] = {};
    for (int kt = 0; kt < INTERSZ / BK; ++kt) {
        const int k0 = kt * BK;
        #pragma unroll
        for (int i = 0; i < 4; ++i) {
            int c = tid + i * 256;
            gl2lds16(A0 + (size_t)row[i] * INTERSZ + k0 + cgs[i], &As[c * 8]);
            gl2lds16(B0 + (size_t)row[i] * INTERSZ + k0 + cgs[i], &Bs[c * 8]);
        }
        __syncthreads();
        #pragma unroll
        for (int ks = 0; ks < 4; ++ks) {
            bf16x8 af[2], bfr[2];
            const int g = ks * 4 + lq;
            #pragma unroll
            for (int mt = 0; mt < 2; ++mt) {
                int m = wm + mt * 16 + lr;
                af[mt] = *(const bf16x8*)&As[(m * CHK + (g ^ (m & 7))) * 8];
            }
            #pragma unroll
            for (int nt = 0; nt < 2; ++nt) {
                int n = wn + nt * 16 + lr;
                bfr[nt] = *(const bf16x8*)&Bs[(n * CHK + (g ^ (n & 7))) * 8];
            }
            #pragma unroll
            for (int mt = 0; mt < 2; ++mt) {
                #pragma unroll
                for (int nt = 0; nt < 2; ++nt) {
                    acc[mt][nt] = __builtin_amdgcn_mfma_f32_16x16x32_bf16(af[mt], bfr[nt], acc[mt][nt], 0, 0, 0);
                }
            }
        }
        __syncthreads();
    }
    #pragma unroll
    for (int mt = 0; mt < 2; ++mt) {
        #pragma unroll
        for (int r = 0; r < 4; ++r) {
            int m = wm + mt * 16 + lq * 4 + r;
            int slot = m0 + m;
            if (slot < cnt) {
                int t = tokidx[e * TTOK + slot];
                float* db = ((topi[t] & 255) == e) ? bufA : bufB;
                #pragma unroll
                for (int nt = 0; nt < 2; ++nt) {
                    int n = wn + nt * 16 + lr;
                    db[(size_t)t * DIMSZ + n0 + n] = acc[mt][nt][r];
                }
            }
        }
    }
}

// ---- GEMM2 shared: BM=64 BN=64 BK=128, K=1024 (R5-proven); epilogue combines
// shared acc + bufA + bufB and writes out once.
__global__ __launch_bounds__(256) void gemm2sh(
    const u16* __restrict__ Hs, const u16* __restrict__ W2sb,
    const float* __restrict__ bufA, const float* __restrict__ bufB,
    float* __restrict__ out) {
    const int m0 = blockIdx.y * 64;
    const int n0 = blockIdx.x * 64;
    __shared__ u16 As[64 * BK], Bs[64 * BK];
    const u16* A0 = Hs + (size_t)m0 * DIMSZ;
    const u16* B0 = W2sb + (size_t)n0 * DIMSZ;
    const int tid = threadIdx.x;
    const int wave = tid >> 6, lane = tid & 63;
    const int wm = (wave >> 1) * 32, wn = (wave & 1) * 32;
    const int lr = lane & 15, lq = lane >> 4;

    int row[4], cgs[4];
    #pragma unroll
    for (int i = 0; i < 4; ++i) {
        int c = tid + i * 256;
        row[i] = c >> 4;
        cgs[i] = ((c & 15) ^ (row[i] & 7)) * 8;
    }

    f32x4 acc[2][2] = {};
    for (int kt = 0; kt < DIMSZ / BK; ++kt) {
        const int k0 = kt * BK;
        #pragma unroll
        for (int i = 0; i < 4; ++i) {
            int c = tid + i * 256;
            gl2lds16(A0 + (size_t)row[i] * DIMSZ + k0 + cgs[i], &As[c * 8]);
            gl2lds16(B0 + (size_t)row[i] * DIMSZ + k0 + cgs[i], &Bs[c * 8]);
        }
        __syncthreads();
        #pragma unroll
        for (int ks = 0; ks < 4; ++ks) {
            bf16x8 af[2], bfr[2];
            const int g = ks * 4 + lq;
            #pragma unroll
            for (int mt = 0; mt < 2; ++mt) {
                int m = wm + mt * 16 + lr;
                af[mt] = *(const bf16x8*)&As[(m * CHK + (g ^ (m & 7))) * 8];
            }
            #pragma unroll
            for (int nt = 0; nt < 2; ++nt) {
                int n = wn + nt * 16 + lr;
                bfr[nt] = *(const bf16x8*)&Bs[(n * CHK + (g ^ (n & 7))) * 8];
            }
            #pragma unroll
            for (int mt = 0; mt < 2; ++mt) {
                #pragma unroll
                for (int nt = 0; nt < 2; ++nt) {
                    acc[mt][nt] = __builtin_amdgcn_mfma_f32_16x16x32_bf16(af[mt], bfr[nt], acc[mt][nt], 0, 0, 0);
                }
            }
        }
        __syncthreads();
    }
    #pragma unroll
    for (int mt = 0; mt < 2; ++mt) {
        #pragma unroll
        for (int r = 0; r < 4; ++r) {
            int t = m0 + wm + mt * 16 + lq * 4 + r;
            #pragma unroll
            for (int nt = 0; nt < 2; ++nt) {
                int n = wn + nt * 16 + lr;
                size_t idx = (size_t)t * DIMSZ + n0 + n;
                out[idx] = acc[mt][nt][r] + bufA[idx] + bufB[idx];
            }
        }
    }
}

extern "C" void kernel_launch(void* const* d_in, const int* in_sizes, int n_in,
                              void* d_out, int out_size, void* d_ws, size_t ws_size,
                              hipStream_t stream) {
    const float* x      = (const float*)d_in[0];
    const float* gate_w = (const float*)d_in[1];
    const float* w1     = (const float*)d_in[2];
    const float* w2     = (const float*)d_in[3];
    const float* w3     = (const float*)d_in[4];
    const float* sw1    = (const float*)d_in[5];
    const float* sw2    = (const float*)d_in[6];
    const float* sw3    = (const float*)d_in[7];
    float* out = (float*)d_out;

    char* ws = (char*)d_ws;
    const size_t SZ_W   = (size_t)(NROUT + 2) * INTERSZ * DIMSZ * 2;
    const size_t SZ_XBF = (size_t)TTOK * DIMSZ * 2;
    u16*   W1b    = (u16*)(ws);
    u16*   W3b    = (u16*)(ws + SZ_W);
    u16*   W2all  = (u16*)(ws + 2 * SZ_W);
    u16*   Xbf    = (u16*)(ws + 3 * SZ_W);
    char*  route  = ws + 3 * SZ_W + SZ_XBF;
    int*   counts = (int*)route;
    int*   topi   = (int*)(route + 256);
    float2* topw  = (float2*)(route + 256 + TTOK * 4);
    int*   tokidx = (int*)(route + 256 + TTOK * 12);
    float* tokw   = (float*)(route + 256 + TTOK * 12 + 16 * TTOK * 4);
    char*  hbuf   = route + 256 + TTOK * 12 + 2 * (size_t)16 * TTOK * 4;
    u16*   Hc     = (u16*)hbuf;                                        // [16][2048][512]
    u16*   Hs     = (u16*)(hbuf + (size_t)NROUT * TTOK * INTERSZ * 2); // [2048][1024]
    char*  bufs   = hbuf + (size_t)NROUT * TTOK * INTERSZ * 2 + (size_t)TTOK * DIMSZ * 2;
    float* bufA   = (float*)bufs;                                      // [2048][1024] fp32
    float* bufB   = (float*)(bufs + (size_t)TTOK * DIMSZ * 4);
    u16*   W2sb   = W2all + (size_t)NROUT * DIMSZ * INTERSZ;

    prep<<<dim3(2048, 4), 256, 0, stream>>>(
        w1, sw1, w3, sw3, w2, sw2, W1b, W3b, W2all,
        x, gate_w, topi, topw, Xbf);
    route_kernel<<<NROUT, 256, 0, stream>>>(topi, topw, counts, tokidx, tokw);
    gemm1s<<<dim3(INTERSZ / 64, TTOK / 128, NROUT + 2), 256, 0, stream>>>(
        Xbf, W1b, W3b, counts, tokidx, tokw, Hc, Hs);
    gemm2rt<<<dim3(DIMSZ / 64, TTOK / 64, NROUT), 256, 0, stream>>>(
        Hc, W2all, counts, tokidx, topi, bufA, bufB);
    gemm2sh<<<dim3(DIMSZ / 64, TTOK / 64), 256, 0, stream>>>(
        Hs, W2sb, bufA, bufB, out);
}